// Round 4
// baseline (477.528 us; speedup 1.0000x reference)
//
#include <hip/hip_runtime.h>
#include <hip/hip_bf16.h>

typedef __bf16 bf16_t;
typedef __bf16 bf16x8 __attribute__((ext_vector_type(8)));
typedef float f32x4 __attribute__((ext_vector_type(4)));

#define BATCH 4
#define NSEQ 2048
#define DMODEL 512
#define HEADS 8
#define DHEAD 64
#define QKVN 1536
#define NN ((size_t)NSEQ * NSEQ)

// LDS-only barrier: does NOT drain vmcnt -> prefetched global loads stay in
// flight across it (all cross-thread comms here are LDS).
#define BAR() asm volatile("s_waitcnt lgkmcnt(0)\n\ts_barrier" ::: "memory")
// Pin: loads issued textually before this cannot sink past it.
#define PIN() asm volatile("" ::: "memory")

__device__ __forceinline__ void gload_lds16(const void* g, void* l) {
  __builtin_amdgcn_global_load_lds((const __attribute__((address_space(1))) void*)g,
                                   (__attribute__((address_space(3))) void*)l, 16, 0, 0);
}

__device__ __forceinline__ f32x4 mfma16(bf16x8 a, bf16x8 b, f32x4 c) {
  return __builtin_amdgcn_mfma_f32_16x16x32_bf16(a, b, c, 0, 0, 0);
}

// ---------------- convert kernels ----------------
__global__ __launch_bounds__(256) void cvt_bf16_kernel(const float* __restrict__ in,
                                                       bf16_t* __restrict__ out, int n4) {
  int i = blockIdx.x * 256 + threadIdx.x;
  if (i < n4) {
    float4 v = ((const float4*)in)[i];
    union { bf16_t b[4]; uint2 u; } pk;
    pk.b[0] = (bf16_t)v.x; pk.b[1] = (bf16_t)v.y;
    pk.b[2] = (bf16_t)v.z; pk.b[3] = (bf16_t)v.w;
    ((uint2*)out)[i] = pk.u;
  }
}

// in[R][C] fp32 -> out[C][R] bf16, LDS-tiled; output rows < scaleRows get *sc
// (used to fold the attention 1/sqrt(d) into Wqkv's Q columns for free).
__global__ __launch_bounds__(256) void cvt_transpose_kernel(const float* __restrict__ in,
                                                            bf16_t* __restrict__ out, int R, int C,
                                                            int scaleRows, float sc) {
  __shared__ float tile[64][65];
  const int r0 = blockIdx.y * 64, c0 = blockIdx.x * 64;
  const int tx = threadIdx.x & 63, tg = threadIdx.x >> 6;
#pragma unroll
  for (int i = 0; i < 16; i++) {
    int rr = tg * 16 + i;
    tile[rr][tx] = in[(size_t)(r0 + rr) * C + c0 + tx];
  }
  __syncthreads();
#pragma unroll
  for (int i = 0; i < 16; i++) {
    int cc = tg * 16 + i;
    float v = tile[tx][cc];
    if (c0 + cc < scaleRows) v *= sc;
    out[(size_t)(c0 + cc) * R + r0 + tx] = (bf16_t)v;
  }
}

// V pre-transpose: vT[b*8+h][d][j] = qkv[b*N+j][1024 + h*64 + d]
// grid: 32 jt-tiles x 32 (b,h) = 1024 blocks
__global__ __launch_bounds__(256) void vtrans_kernel(const bf16_t* __restrict__ qkv,
                                                     bf16_t* __restrict__ vT) {
  __shared__ bf16_t tile[64][72];
  const int bh = blockIdx.x & 31, jt = blockIdx.x >> 5;
  const int b = bh >> 3, h = bh & 7;
  const int tid = threadIdx.x;
#pragma unroll
  for (int i = 0; i < 2; i++) {
    int g = tid * 2 + i, row = g >> 3, gr = g & 7;
    *(uint4*)&tile[row][gr * 8] =
        *(const uint4*)&qkv[(size_t)(b * NSEQ + jt * 64 + row) * QKVN + 2 * DMODEL + h * DHEAD + gr * 8];
  }
  __syncthreads();
#pragma unroll
  for (int i = 0; i < 2; i++) {
    int g = tid * 2 + i, d = g >> 3, jg = g & 7;
    union { bf16_t e[8]; uint4 u; } pk;
#pragma unroll
    for (int e2 = 0; e2 < 8; e2++) pk.e[e2] = tile[jg * 8 + e2][d];
    *(uint4*)&vT[(size_t)(bh * 64 + d) * NSEQ + jt * 64 + jg * 8] = pk.u;
  }
}

// ---------------- GEMM: C[M,N] = A[M,K] * Bt[N,K]^T (+bias) ----------------
template<int BIAS, int OUTF32>
__global__ __launch_bounds__(256) void gemm128_kernel(const bf16_t* __restrict__ A,
    const bf16_t* __restrict__ Bt, void* __restrict__ Cout,
    const float* __restrict__ bias, int M, int N, int K) {
  __shared__ __align__(16) bf16_t As[128 * 64];
  __shared__ __align__(16) bf16_t Bs[128 * 64];
  const int tid = threadIdx.x;
  const int w = tid >> 6, lane = tid & 63, quad = lane >> 4, l16 = lane & 15;
  const int wm = w & 1, wn = w >> 1;
  const int m0 = blockIdx.x * 128, n0 = blockIdx.y * 128;
  f32x4 acc[4][4] = {};
  int srow[4], scg[4];
#pragma unroll
  for (int t = 0; t < 4; t++) {
    int s = (w * 4 + t) * 64 + lane;
    srow[t] = s >> 3;
    scg[t] = (s & 7) ^ (srow[t] & 7);
  }
  for (int k0 = 0; k0 < K; k0 += 64) {
#pragma unroll
    for (int t = 0; t < 4; t++) {
      gload_lds16(&A[(size_t)(m0 + srow[t]) * K + k0 + scg[t] * 8], &As[(w * 4 + t) * 512]);
      gload_lds16(&Bt[(size_t)(n0 + srow[t]) * K + k0 + scg[t] * 8], &Bs[(w * 4 + t) * 512]);
    }
    __syncthreads();
    bf16x8 af[4][2], bfr[4][2];
#pragma unroll
    for (int mt = 0; mt < 4; mt++) {
      int row = wm * 64 + mt * 16 + l16;
#pragma unroll
      for (int kh = 0; kh < 2; kh++)
        af[mt][kh] = *(const bf16x8*)&As[(row * 8 + ((kh * 4 + quad) ^ (row & 7))) * 8];
    }
#pragma unroll
    for (int nt = 0; nt < 4; nt++) {
      int row = wn * 64 + nt * 16 + l16;
#pragma unroll
      for (int kh = 0; kh < 2; kh++)
        bfr[nt][kh] = *(const bf16x8*)&Bs[(row * 8 + ((kh * 4 + quad) ^ (row & 7))) * 8];
    }
#pragma unroll
    for (int mt = 0; mt < 4; mt++)
#pragma unroll
      for (int nt = 0; nt < 4; nt++) {
        acc[mt][nt] = mfma16(af[mt][0], bfr[nt][0], acc[mt][nt]);
        acc[mt][nt] = mfma16(af[mt][1], bfr[nt][1], acc[mt][nt]);
      }
    __syncthreads();
  }
#pragma unroll
  for (int nt = 0; nt < 4; nt++) {
    int col = n0 + wn * 64 + nt * 16 + l16;
    float bv = BIAS ? bias[col] : 0.0f;
#pragma unroll
    for (int mt = 0; mt < 4; mt++) {
#pragma unroll
      for (int rr = 0; rr < 4; rr++) {
        int row = m0 + wm * 64 + mt * 16 + quad * 4 + rr;
        float v = acc[mt][nt][rr] + bv;
        if (OUTF32) ((float*)Cout)[(size_t)row * N + col] = v;
        else        ((bf16_t*)Cout)[(size_t)row * N + col] = (bf16_t)v;
      }
    }
  }
}

// ---------------- fused flash attention with conv-bias ----------------
// grid: 1024 blocks; bid = h*128 + b*32 + it (head-siblings -> same XCD for
// cd L2 dedupe). 4 waves; wave w owns Q rows [it*64 + w*16, +16).
// Pipelining: raw cd (48 regs) + K/V (16 regs) loaded one j-tile ahead,
// pinned in the early window by BAR's and PIN's memory clobbers; combined
// at consumption the next iteration. launch_bounds(256,3) -> VGPR cap 170
// so the allocator keeps them (R3's cap of 128 made it sink everything).
__global__ __launch_bounds__(256, 3) void attn_kernel(const bf16_t* __restrict__ qkv,
    const bf16_t* __restrict__ vT, const float* __restrict__ cd,
    const float* __restrict__ rel_w, const float* __restrict__ rel_b,
    bf16_t* __restrict__ ao) {
  __shared__ __align__(16) bf16_t Ks[64][72];   // K tile: [j][d]
  __shared__ __align__(16) bf16_t Vts[64][72];  // V^T tile: [d][j] (from vT, b128)
  __shared__ __align__(16) bf16_t Ps[64][72];   // P: [i][j], col XOR-swizzled
  const int tid = threadIdx.x;
  const int w = tid >> 6, lane = tid & 63, quad = lane >> 4, l16 = lane & 15;
  const int bid = blockIdx.x;
  const int h = bid >> 7, b = (bid >> 5) & 3, it = bid & 31;
  const int bh = b * 8 + h;

  // Q fragments (A-layout); Wqkv Q-columns were pre-scaled by 1/8.
  const size_t qoff = (size_t)(b * NSEQ + it * 64 + w * 16 + l16) * QKVN + h * DHEAD;
  bf16x8 q0 = *(const bf16x8*)&qkv[qoff + quad * 8];
  bf16x8 q1 = *(const bf16x8*)&qkv[qoff + 32 + quad * 8];

  const float rw0 = rel_w[h * 3 + 0], rw1 = rel_w[h * 3 + 1], rw2 = rel_w[h * 3 + 2];
  const float rb = rel_b[h];

  f32x4 o[4] = {};
  float m_r[4], l_r[4];
#pragma unroll
  for (int r = 0; r < 4; r++) { m_r[r] = -1e30f; l_r[r] = 0.0f; }

  const int sr = tid >> 3, sg = tid & 7;
  const size_t kbase = (size_t)b * NSEQ * QKVN + DMODEL + h * DHEAD;
  const bf16_t* vbase = vT + (size_t)(bh * 64) * NSEQ;

  const int row0 = it * 64 + w * 16 + quad * 4;
  const float* cdp = cd + (size_t)b * 3 * NN + (size_t)row0 * NSEQ + l16;

  // ---- prologue: tile 0 K/V and raw cd into registers ----
  uint4 k0r, k1r, v0r, v1r;
  {
    const bf16_t* p = &qkv[kbase + (size_t)sr * QKVN + sg * 8];
    k0r = *(const uint4*)p;
    k1r = *(const uint4*)(p + (size_t)32 * QKVN);
    v0r = *(const uint4*)&vbase[(size_t)sr * NSEQ + sg * 8];
    v1r = *(const uint4*)&vbase[(size_t)(sr + 32) * NSEQ + sg * 8];
  }
  float cdr[3][4][4];
#pragma unroll
  for (int ch = 0; ch < 3; ch++)
#pragma unroll
    for (int ct = 0; ct < 4; ct++)
#pragma unroll
      for (int r = 0; r < 4; r++)
        cdr[ch][ct][r] = cdp[ch * NN + (size_t)r * NSEQ + ct * 16];

  for (int jt = 0; jt < 32; jt++) {
    // ---- staged regs -> LDS ----
    *(uint4*)&Ks[sr][sg * 8]       = k0r;
    *(uint4*)&Ks[sr + 32][sg * 8]  = k1r;
    *(uint4*)&Vts[sr][sg * 8]      = v0r;
    *(uint4*)&Vts[sr + 32][sg * 8] = v1r;
    BAR();

    // ---- prefetch next K/V tile (full-iteration slack) ----
    if (jt < 31) {
      const bf16_t* p = &qkv[kbase + (size_t)((jt + 1) * 64 + sr) * QKVN + sg * 8];
      k0r = *(const uint4*)p;
      k1r = *(const uint4*)(p + (size_t)32 * QKVN);
      v0r = *(const uint4*)&vbase[(size_t)sr * NSEQ + (jt + 1) * 64 + sg * 8];
      v1r = *(const uint4*)&vbase[(size_t)(sr + 32) * NSEQ + (jt + 1) * 64 + sg * 8];
    }

    // ---- combine current cd -> softmax-logit accumulator init ----
    f32x4 s[4];
#pragma unroll
    for (int ct = 0; ct < 4; ct++)
#pragma unroll
      for (int r = 0; r < 4; r++)
        s[ct][r] = fmaf(rw0, cdr[0][ct][r],
                   fmaf(rw1, cdr[1][ct][r], fmaf(rw2, cdr[2][ct][r], rb)));

    // ---- prefetch next cd tile (raw, combined next iteration) ----
    if (jt < 31) {
      const size_t jb = (size_t)(jt + 1) * 64;
#pragma unroll
      for (int ch = 0; ch < 3; ch++)
#pragma unroll
        for (int ct = 0; ct < 4; ct++)
#pragma unroll
          for (int r = 0; r < 4; r++)
            cdr[ch][ct][r] = cdp[ch * NN + (size_t)r * NSEQ + jb + ct * 16];
    }
    PIN();   // loads above cannot sink past this point

    // ---- S = bias + Q*K^T (bias pre-loaded into the accumulator) ----
#pragma unroll
    for (int ct = 0; ct < 4; ct++) {
      bf16x8 b0 = *(const bf16x8*)&Ks[ct * 16 + l16][quad * 8];
      bf16x8 b1 = *(const bf16x8*)&Ks[ct * 16 + l16][32 + quad * 8];
      s[ct] = mfma16(q0, b0, s[ct]);
      s[ct] = mfma16(q1, b1, s[ct]);
    }

    // ---- online softmax (per quad-row) ----
#pragma unroll
    for (int r = 0; r < 4; r++) {
      float mx = fmaxf(fmaxf(s[0][r], s[1][r]), fmaxf(s[2][r], s[3][r]));
#pragma unroll
      for (int off = 8; off >= 1; off >>= 1) mx = fmaxf(mx, __shfl_xor(mx, off, 64));
      float mnew = fmaxf(m_r[r], mx);
      float alpha = __expf(m_r[r] - mnew);
      float rsum = 0.0f;
#pragma unroll
      for (int ct = 0; ct < 4; ct++) {
        float p = __expf(s[ct][r] - mnew);
        s[ct][r] = p; rsum += p;
      }
#pragma unroll
      for (int off = 8; off >= 1; off >>= 1) rsum += __shfl_xor(rsum, off, 64);
      l_r[r] = l_r[r] * alpha + rsum;
      m_r[r] = mnew;
#pragma unroll
      for (int dt = 0; dt < 4; dt++) o[dt][r] *= alpha;
    }

    // ---- P: C-layout -> LDS (swizzled) -> A-layout (wave-private slice) ----
#pragma unroll
    for (int ct = 0; ct < 4; ct++)
#pragma unroll
      for (int rr = 0; rr < 4; rr++)
        Ps[w * 16 + quad * 4 + rr][(ct * 16 + l16) ^ (quad << 3)] = (bf16_t)s[ct][rr];

    const int psw = ((l16 >> 2) & 3) << 3;
    bf16x8 p0 = *(const bf16x8*)&Ps[w * 16 + l16][(quad * 8) ^ psw];
    bf16x8 p1 = *(const bf16x8*)&Ps[w * 16 + l16][32 + ((quad * 8) ^ psw)];
#pragma unroll
    for (int dt = 0; dt < 4; dt++) {
      bf16x8 v0 = *(const bf16x8*)&Vts[dt * 16 + l16][quad * 8];
      bf16x8 v1 = *(const bf16x8*)&Vts[dt * 16 + l16][32 + quad * 8];
      o[dt] = mfma16(p0, v0, o[dt]);
      o[dt] = mfma16(p1, v1, o[dt]);
    }
    BAR();   // readers done before next iteration's staging writes
  }

  // ---- epilogue ----
  float inv[4];
#pragma unroll
  for (int r = 0; r < 4; r++) inv[r] = 1.0f / l_r[r];
#pragma unroll
  for (int dt = 0; dt < 4; dt++) {
    int col = h * DHEAD + dt * 16 + l16;
#pragma unroll
    for (int rr = 0; rr < 4; rr++) {
      int row = b * NSEQ + it * 64 + w * 16 + quad * 4 + rr;
      ao[(size_t)row * DMODEL + col] = (bf16_t)(o[dt][rr] * inv[rr]);
    }
  }
}

// ---------------- launch ----------------
extern "C" void kernel_launch(void* const* d_in, const int* in_sizes, int n_in,
                              void* d_out, int out_size, void* d_ws, size_t ws_size,
                              hipStream_t stream) {
  const float* x     = (const float*)d_in[0];
  const float* cd    = (const float*)d_in[1];
  const float* Wqkv  = (const float*)d_in[2];
  const float* Wout  = (const float*)d_in[3];
  const float* bout  = (const float*)d_in[4];
  const float* rel_w = (const float*)d_in[5];
  const float* rel_b = (const float*)d_in[6];
  float* out = (float*)d_out;

  char* ws = (char*)d_ws;
  const size_t M = (size_t)BATCH * NSEQ;                 // 8192
  bf16_t* xb    = (bf16_t*)ws;                                            // 8.0 MB
  bf16_t* WqkvT = (bf16_t*)(ws + 8388608);                                // 1.5 MB
  bf16_t* WoutT = (bf16_t*)(ws + 8388608 + 1572864);                      // 0.5 MB
  bf16_t* qkv   = (bf16_t*)(ws + 8388608 + 1572864 + 524288);             // 24 MB
  bf16_t* ao    = (bf16_t*)(ws + 8388608 + 1572864 + 524288 + 25165824);  // 8 MB
  bf16_t* vT    = (bf16_t*)(ws + 8388608 + 1572864 + 524288 + 25165824 + 8388608); // 8 MB

  cvt_bf16_kernel<<<(int)(M * DMODEL / 4 / 256), 256, 0, stream>>>(x, xb, (int)(M * DMODEL / 4));
  // fold softmax scale 1/8 into Wqkv's Q columns (output rows < 512)
  cvt_transpose_kernel<<<dim3(QKVN / 64, DMODEL / 64), 256, 0, stream>>>(
      Wqkv, WqkvT, DMODEL, QKVN, DMODEL, 0.125f);
  cvt_transpose_kernel<<<dim3(DMODEL / 64, DMODEL / 64), 256, 0, stream>>>(
      Wout, WoutT, DMODEL, DMODEL, 0, 1.0f);

  gemm128_kernel<0, 0><<<dim3(M / 128, QKVN / 128), 256, 0, stream>>>(
      xb, WqkvT, (void*)qkv, nullptr, (int)M, QKVN, DMODEL);

  vtrans_kernel<<<1024, 256, 0, stream>>>(qkv, vT);

  attn_kernel<<<BATCH * 32 * HEADS, 256, 0, stream>>>(qkv, vT, cd, rel_w, rel_b, ao);

  gemm128_kernel<1, 1><<<dim3(M / 128, DMODEL / 128), 256, 0, stream>>>(
      ao, WoutT, (void*)out, bout, (int)M, DMODEL, DMODEL);
}